// Round 1
// baseline (2257.903 us; speedup 1.0000x reference)
//
#include <hip/hip_runtime.h>
#include <hip/hip_bf16.h>
#include <cstdint>

// ---------------------------------------------------------------------------
// InitialContextualNodeModel
//   fwd_agg   = segment_mean(edge_attr, edge_index[1], N)
//   bwd_agg   = segment_mean(edge_attr, edge_index[0], N)
//   frame_agg = segment_mean([sf_attr;sf_attr], [early;later], N)
//   out = relu([fwd,frame,bwd] @ W1 + b1) @ W2 + b2
// D_EDGE = 64, N = 50000, E = 800000, Es = 400000
// ---------------------------------------------------------------------------

#define D 64

// ---- scatter: temporal edges -> fwd (by future) and bwd (by past) ----------
__global__ __launch_bounds__(256) void scatter_edges_kernel(
    const int* __restrict__ ei, const float* __restrict__ attr,
    float* __restrict__ fwd_sum, float* __restrict__ bwd_sum,
    float* __restrict__ fwd_cnt, float* __restrict__ bwd_cnt, int E)
{
    long long t = (long long)blockIdx.x * blockDim.x + threadIdx.x;
    int e = (int)(t >> 4);          // 16 threads per edge
    if (e >= E) return;
    int j = ((int)t & 15) * 4;      // feature quad

    int past = ei[e];
    int fut  = ei[E + e];
    float4 v = *reinterpret_cast<const float4*>(&attr[(size_t)e * D + j]);

    float* fs = &fwd_sum[(size_t)fut * D + j];
    atomicAdd(fs + 0, v.x); atomicAdd(fs + 1, v.y);
    atomicAdd(fs + 2, v.z); atomicAdd(fs + 3, v.w);

    float* bs = &bwd_sum[(size_t)past * D + j];
    atomicAdd(bs + 0, v.x); atomicAdd(bs + 1, v.y);
    atomicAdd(bs + 2, v.z); atomicAdd(bs + 3, v.w);

    if (((int)t & 15) == 0) {
        atomicAdd(&fwd_cnt[fut], 1.0f);
        atomicAdd(&bwd_cnt[past], 1.0f);
    }
}

// ---- scatter: same-frame edges -> frame agg (both endpoints) ---------------
__global__ __launch_bounds__(256) void scatter_sf_kernel(
    const int* __restrict__ ei, const float* __restrict__ attr,
    float* __restrict__ f_sum, float* __restrict__ f_cnt, int Es)
{
    long long t = (long long)blockIdx.x * blockDim.x + threadIdx.x;
    int e = (int)(t >> 4);
    if (e >= Es) return;
    int j = ((int)t & 15) * 4;

    int early = ei[e];
    int later = ei[Es + e];
    float4 v = *reinterpret_cast<const float4*>(&attr[(size_t)e * D + j]);

    float* s0 = &f_sum[(size_t)early * D + j];
    atomicAdd(s0 + 0, v.x); atomicAdd(s0 + 1, v.y);
    atomicAdd(s0 + 2, v.z); atomicAdd(s0 + 3, v.w);

    float* s1 = &f_sum[(size_t)later * D + j];
    atomicAdd(s1 + 0, v.x); atomicAdd(s1 + 1, v.y);
    atomicAdd(s1 + 2, v.z); atomicAdd(s1 + 3, v.w);

    if (((int)t & 15) == 0) {
        atomicAdd(&f_cnt[early], 1.0f);
        atomicAdd(&f_cnt[later], 1.0f);
    }
}

// ---- fused mean + MLP ------------------------------------------------------
// 64 nodes per block, 256 threads. LDS holds flow^T [192][65] (padded),
// reused for h^T [128][65].
#define MLP_NODES 64
#define LDS_PITCH 65

__global__ __launch_bounds__(256) void mlp_kernel(
    const float* __restrict__ sums,   // [3][N][64] (fwd, frame, bwd)
    const float* __restrict__ cnts,   // [3][N]
    const float* __restrict__ W1, const float* __restrict__ b1,
    const float* __restrict__ W2, const float* __restrict__ b2,
    float* __restrict__ out, int N)
{
    __shared__ float lds[192 * LDS_PITCH];   // 49.9 KB

    int t = threadIdx.x;
    int nbase = blockIdx.x * MLP_NODES;

    // Phase 1: flow^T into LDS (flow = [fwd | frame | bwd] per node, length 192)
    for (int s = 0; s < 3; ++s) {
        const float* S = sums + (size_t)s * N * D;
        const float* C = cnts + (size_t)s * N;
        for (int idx = t; idx < MLP_NODES * D; idx += 256) {
            int ln = idx >> 6;         // local node
            int j  = idx & 63;         // feature
            int node = nbase + ln;
            float v = 0.0f;
            if (node < N) {
                float c = C[node];
                v = S[(size_t)node * D + j] * (1.0f / fmaxf(c, 1.0f));
            }
            lds[(s * D + j) * LDS_PITCH + ln] = v;
        }
    }
    __syncthreads();

    // Phase 2: h = relu(flow @ W1 + b1).  M=64 nodes, Ncols=128, K=192.
    // thread -> 4 nodes x 8 cols
    int tn = t & 15;            // node group
    int tc = t >> 4;            // col group (0..15)
    int n0 = tn * 4;
    int c0 = tc * 8;

    float acc[4][8];
#pragma unroll
    for (int a = 0; a < 4; ++a)
#pragma unroll
        for (int b = 0; b < 8; ++b) acc[a][b] = 0.0f;

    for (int i = 0; i < 192; ++i) {
        float4 fv = *reinterpret_cast<const float4*>(&lds[i * LDS_PITCH + n0]);
        float4 wa = *reinterpret_cast<const float4*>(&W1[i * 128 + c0]);
        float4 wb = *reinterpret_cast<const float4*>(&W1[i * 128 + c0 + 4]);
        float f[4] = {fv.x, fv.y, fv.z, fv.w};
        float w[8] = {wa.x, wa.y, wa.z, wa.w, wb.x, wb.y, wb.z, wb.w};
#pragma unroll
        for (int a = 0; a < 4; ++a)
#pragma unroll
            for (int b = 0; b < 8; ++b)
                acc[a][b] += f[a] * w[b];
    }
    __syncthreads();   // all reads of flow^T done; LDS about to be reused

    // relu + bias, write h^T [128][65]
#pragma unroll
    for (int b = 0; b < 8; ++b) {
        int col = c0 + b;
        float bias = b1[col];
        float4 hv;
        hv.x = fmaxf(acc[0][b] + bias, 0.0f);
        hv.y = fmaxf(acc[1][b] + bias, 0.0f);
        hv.z = fmaxf(acc[2][b] + bias, 0.0f);
        hv.w = fmaxf(acc[3][b] + bias, 0.0f);
        *reinterpret_cast<float4*>(&lds[col * LDS_PITCH + n0]) = hv;
    }
    __syncthreads();

    // Phase 3: out = h @ W2 + b2.  K=128, 64 cols. thread -> 4 nodes x 4 cols
    int c20 = tc * 4;
    float acc2[4][4];
#pragma unroll
    for (int a = 0; a < 4; ++a)
#pragma unroll
        for (int b = 0; b < 4; ++b) acc2[a][b] = 0.0f;

    for (int i = 0; i < 128; ++i) {
        float4 hv = *reinterpret_cast<const float4*>(&lds[i * LDS_PITCH + n0]);
        float4 wv = *reinterpret_cast<const float4*>(&W2[i * 64 + c20]);
        float h[4] = {hv.x, hv.y, hv.z, hv.w};
        float w[4] = {wv.x, wv.y, wv.z, wv.w};
#pragma unroll
        for (int a = 0; a < 4; ++a)
#pragma unroll
            for (int b = 0; b < 4; ++b)
                acc2[a][b] += h[a] * w[b];
    }

    float4 bb = *reinterpret_cast<const float4*>(&b2[c20]);
#pragma unroll
    for (int a = 0; a < 4; ++a) {
        int node = nbase + n0 + a;
        if (node < N) {
            float4 o;
            o.x = acc2[a][0] + bb.x;
            o.y = acc2[a][1] + bb.y;
            o.z = acc2[a][2] + bb.z;
            o.w = acc2[a][3] + bb.w;
            *reinterpret_cast<float4*>(&out[(size_t)node * D + c20]) = o;
        }
    }
}

// ---------------------------------------------------------------------------
extern "C" void kernel_launch(void* const* d_in, const int* in_sizes, int n_in,
                              void* d_out, int out_size, void* d_ws, size_t ws_size,
                              hipStream_t stream)
{
    const int*   edge_index = (const int*)d_in[0];
    const float* edge_attr  = (const float*)d_in[1];
    const int*   sf_index   = (const int*)d_in[3];
    const float* sf_attr    = (const float*)d_in[4];
    const float* W1         = (const float*)d_in[5];
    const float* b1         = (const float*)d_in[6];
    const float* W2         = (const float*)d_in[7];
    const float* b2         = (const float*)d_in[8];
    float* out = (float*)d_out;

    int E  = in_sizes[0] / 2;
    int Es = in_sizes[3] / 2;
    int N  = out_size / D;

    // Workspace layout: [3][N][64] sums, then [3][N] counts (all f32)
    float* ws = (float*)d_ws;
    float* fwd_sum   = ws;
    float* frame_sum = ws + (size_t)N * D;
    float* bwd_sum   = ws + (size_t)2 * N * D;
    float* fwd_cnt   = ws + (size_t)3 * N * D;
    float* frame_cnt = fwd_cnt + N;
    float* bwd_cnt   = frame_cnt + N;

    size_t zero_bytes = ((size_t)3 * N * D + (size_t)3 * N) * sizeof(float);
    hipMemsetAsync(d_ws, 0, zero_bytes, stream);

    {
        long long threads = (long long)E * 16;
        int blocks = (int)((threads + 255) / 256);
        scatter_edges_kernel<<<blocks, 256, 0, stream>>>(
            edge_index, edge_attr, fwd_sum, bwd_sum, fwd_cnt, bwd_cnt, E);
    }
    {
        long long threads = (long long)Es * 16;
        int blocks = (int)((threads + 255) / 256);
        scatter_sf_kernel<<<blocks, 256, 0, stream>>>(
            sf_index, sf_attr, frame_sum, frame_cnt, Es);
    }
    {
        int blocks = (N + MLP_NODES - 1) / MLP_NODES;
        mlp_kernel<<<blocks, 256, 0, stream>>>(
            fwd_sum, fwd_cnt, W1, b1, W2, b2, out, N);
    }
}

// Round 2
// 719.117 us; speedup vs baseline: 3.1398x; 3.1398x over previous
//
#include <hip/hip_runtime.h>
#include <hip/hip_bf16.h>
#include <cstdint>

// ---------------------------------------------------------------------------
// InitialContextualNodeModel — CSR-gather version
//   flow[n] = [ fwd_mean(n) | frame_mean(n) | bwd_mean(n) ]   (192 f32)
//   out = relu(flow @ W1 + b1) @ W2 + b2
// Sections: s=0 fwd (key=future), s=1 frame (keys early+later), s=2 bwd (key=past)
// ---------------------------------------------------------------------------

#define D 64

// ---- degree counting -------------------------------------------------------
__global__ __launch_bounds__(256) void count_temporal_kernel(
    const int* __restrict__ ei, int* __restrict__ cnt, int E, int N)
{
    int e = blockIdx.x * blockDim.x + threadIdx.x;
    if (e >= E) return;
    int past = ei[e];
    int fut  = ei[E + e];
    atomicAdd(&cnt[fut], 1);            // s=0
    atomicAdd(&cnt[2 * N + past], 1);   // s=2
}

__global__ __launch_bounds__(256) void count_sf_kernel(
    const int* __restrict__ ei, int* __restrict__ cnt, int Es, int N)
{
    int e = blockIdx.x * blockDim.x + threadIdx.x;
    if (e >= Es) return;
    atomicAdd(&cnt[N + ei[e]], 1);        // s=1 early
    atomicAdd(&cnt[N + ei[Es + e]], 1);   // s=1 later
}

// ---- single-block exclusive scan over T elements ---------------------------
__global__ __launch_bounds__(1024) void scan_kernel(
    const int* __restrict__ cnt, int* __restrict__ off, int T)
{
    __shared__ int part[1024];
    int t = threadIdx.x;
    int chunk = (T + 1023) >> 10;
    int lo = t * chunk;
    int hi = min(lo + chunk, T);
    int s = 0;
    for (int i = lo; i < hi; ++i) s += cnt[i];
    part[t] = s;
    __syncthreads();
    for (int d = 1; d < 1024; d <<= 1) {
        int v = 0;
        if (t >= d) v = part[t - d];
        __syncthreads();
        if (t >= d) part[t] += v;
        __syncthreads();
    }
    int run = (t == 0) ? 0 : part[t - 1];
    for (int i = lo; i < hi; ++i) { off[i] = run; run += cnt[i]; }
    if (t == 1023) off[T] = part[1023];
}

// ---- CSR fill --------------------------------------------------------------
__global__ __launch_bounds__(256) void fill_temporal_kernel(
    const int* __restrict__ ei, const int* __restrict__ off,
    int* __restrict__ cur, int* __restrict__ list, int E, int N)
{
    int e = blockIdx.x * blockDim.x + threadIdx.x;
    if (e >= E) return;
    int past = ei[e];
    int fut  = ei[E + e];
    int g0 = fut;
    list[off[g0] + atomicAdd(&cur[g0], 1)] = e;
    int g2 = 2 * N + past;
    list[off[g2] + atomicAdd(&cur[g2], 1)] = e;
}

__global__ __launch_bounds__(256) void fill_sf_kernel(
    const int* __restrict__ ei, const int* __restrict__ off,
    int* __restrict__ cur, int* __restrict__ list, int Es, int N)
{
    int e = blockIdx.x * blockDim.x + threadIdx.x;
    if (e >= Es) return;
    int g = N + ei[e];
    list[off[g] + atomicAdd(&cur[g], 1)] = e;
    g = N + ei[Es + e];
    list[off[g] + atomicAdd(&cur[g], 1)] = e;
}

// ---- gather: one wave per (section,node) segment ---------------------------
__global__ __launch_bounds__(256) void gather_kernel(
    const float* __restrict__ edge_attr, const float* __restrict__ sf_attr,
    const int* __restrict__ off, const int* __restrict__ list,
    float* __restrict__ flow, int N)
{
    int wid  = (blockIdx.x * 256 + threadIdx.x) >> 6;   // segment id
    int lane = threadIdx.x & 63;                        // feature
    if (wid >= 3 * N) return;
    int s = wid / N;
    int node = wid - s * N;
    const float* attr = (s == 1) ? sf_attr : edge_attr;

    int k0 = off[wid], k1 = off[wid + 1];
    float acc = 0.0f;
    int k = k0;
    for (; k + 3 < k1; k += 4) {
        int e0 = list[k], e1 = list[k + 1], e2 = list[k + 2], e3 = list[k + 3];
        float v0 = attr[(size_t)e0 * D + lane];
        float v1 = attr[(size_t)e1 * D + lane];
        float v2 = attr[(size_t)e2 * D + lane];
        float v3 = attr[(size_t)e3 * D + lane];
        acc += v0 + v1 + v2 + v3;
    }
    for (; k < k1; ++k)
        acc += attr[(size_t)list[k] * D + lane];

    int deg = k1 - k0;
    float inv = 1.0f / fmaxf((float)deg, 1.0f);
    flow[(size_t)node * 192 + s * D + lane] = acc * inv;
}

// ---- fallback scatter (only used if ws_size is too small) ------------------
__global__ __launch_bounds__(256) void scatter_temporal_fb_kernel(
    const int* __restrict__ ei, const float* __restrict__ attr,
    float* __restrict__ flow, float* __restrict__ cnt, int E, int N)
{
    long long t = (long long)blockIdx.x * blockDim.x + threadIdx.x;
    int e = (int)(t >> 4);
    if (e >= E) return;
    int j = ((int)t & 15) * 4;
    int past = ei[e];
    int fut  = ei[E + e];
    float4 v = *reinterpret_cast<const float4*>(&attr[(size_t)e * D + j]);
    float* fs = &flow[(size_t)fut * 192 + j];            // s=0
    atomicAdd(fs + 0, v.x); atomicAdd(fs + 1, v.y);
    atomicAdd(fs + 2, v.z); atomicAdd(fs + 3, v.w);
    float* bs = &flow[(size_t)past * 192 + 128 + j];     // s=2
    atomicAdd(bs + 0, v.x); atomicAdd(bs + 1, v.y);
    atomicAdd(bs + 2, v.z); atomicAdd(bs + 3, v.w);
    if (((int)t & 15) == 0) {
        atomicAdd(&cnt[fut], 1.0f);
        atomicAdd(&cnt[2 * N + past], 1.0f);
    }
}

__global__ __launch_bounds__(256) void scatter_sf_fb_kernel(
    const int* __restrict__ ei, const float* __restrict__ attr,
    float* __restrict__ flow, float* __restrict__ cnt, int Es, int N)
{
    long long t = (long long)blockIdx.x * blockDim.x + threadIdx.x;
    int e = (int)(t >> 4);
    if (e >= Es) return;
    int j = ((int)t & 15) * 4;
    int early = ei[e];
    int later = ei[Es + e];
    float4 v = *reinterpret_cast<const float4*>(&attr[(size_t)e * D + j]);
    float* s0 = &flow[(size_t)early * 192 + 64 + j];     // s=1
    atomicAdd(s0 + 0, v.x); atomicAdd(s0 + 1, v.y);
    atomicAdd(s0 + 2, v.z); atomicAdd(s0 + 3, v.w);
    float* s1 = &flow[(size_t)later * 192 + 64 + j];
    atomicAdd(s1 + 0, v.x); atomicAdd(s1 + 1, v.y);
    atomicAdd(s1 + 2, v.z); atomicAdd(s1 + 3, v.w);
    if (((int)t & 15) == 0) {
        atomicAdd(&cnt[N + early], 1.0f);
        atomicAdd(&cnt[N + later], 1.0f);
    }
}

__global__ __launch_bounds__(256) void normalize_fb_kernel(
    float* __restrict__ flow, const float* __restrict__ cnt, int N)
{
    int idx = blockIdx.x * blockDim.x + threadIdx.x;
    if (idx >= N * 192) return;
    int node = idx / 192;
    int i = idx - node * 192;
    int s = i >> 6;
    float c = cnt[s * N + node];
    flow[idx] *= 1.0f / fmaxf(c, 1.0f);
}

// ---- fused MLP: 64 nodes/block, flow^T staged in LDS -----------------------
#define MLP_NODES 64
#define LDS_PITCH 65

__global__ __launch_bounds__(256) void mlp_kernel(
    const float* __restrict__ flow,   // [N][192] means
    const float* __restrict__ W1, const float* __restrict__ b1,
    const float* __restrict__ W2, const float* __restrict__ b2,
    float* __restrict__ out, int N)
{
    __shared__ float lds[192 * LDS_PITCH];

    int t = threadIdx.x;
    int nbase = blockIdx.x * MLP_NODES;

    // Phase 1: flow^T into LDS, float4 loads
    const float4* flow4 = reinterpret_cast<const float4*>(flow);
    for (int idx = t; idx < MLP_NODES * 48; idx += 256) {
        int ln = idx / 48;
        int q  = idx - ln * 48;
        int node = nbase + ln;
        float4 v = make_float4(0.f, 0.f, 0.f, 0.f);
        if (node < N) v = flow4[(size_t)node * 48 + q];
        int i = q * 4;
        lds[(i + 0) * LDS_PITCH + ln] = v.x;
        lds[(i + 1) * LDS_PITCH + ln] = v.y;
        lds[(i + 2) * LDS_PITCH + ln] = v.z;
        lds[(i + 3) * LDS_PITCH + ln] = v.w;
    }
    __syncthreads();

    // Phase 2: h = relu(flow @ W1 + b1).  M=64, Ncols=128, K=192
    int tn = t & 15;
    int tc = t >> 4;
    int n0 = tn * 4;
    int c0 = tc * 8;

    float acc[4][8];
#pragma unroll
    for (int a = 0; a < 4; ++a)
#pragma unroll
        for (int b = 0; b < 8; ++b) acc[a][b] = 0.0f;

    for (int i = 0; i < 192; ++i) {
        float4 fv = *reinterpret_cast<const float4*>(&lds[i * LDS_PITCH + n0]);
        float4 wa = *reinterpret_cast<const float4*>(&W1[i * 128 + c0]);
        float4 wb = *reinterpret_cast<const float4*>(&W1[i * 128 + c0 + 4]);
        float f[4] = {fv.x, fv.y, fv.z, fv.w};
        float w[8] = {wa.x, wa.y, wa.z, wa.w, wb.x, wb.y, wb.z, wb.w};
#pragma unroll
        for (int a = 0; a < 4; ++a)
#pragma unroll
            for (int b = 0; b < 8; ++b)
                acc[a][b] += f[a] * w[b];
    }
    __syncthreads();

#pragma unroll
    for (int b = 0; b < 8; ++b) {
        int col = c0 + b;
        float bias = b1[col];
        float4 hv;
        hv.x = fmaxf(acc[0][b] + bias, 0.0f);
        hv.y = fmaxf(acc[1][b] + bias, 0.0f);
        hv.z = fmaxf(acc[2][b] + bias, 0.0f);
        hv.w = fmaxf(acc[3][b] + bias, 0.0f);
        *reinterpret_cast<float4*>(&lds[col * LDS_PITCH + n0]) = hv;
    }
    __syncthreads();

    // Phase 3: out = h @ W2 + b2.  K=128
    int c20 = tc * 4;
    float acc2[4][4];
#pragma unroll
    for (int a = 0; a < 4; ++a)
#pragma unroll
        for (int b = 0; b < 4; ++b) acc2[a][b] = 0.0f;

    for (int i = 0; i < 128; ++i) {
        float4 hv = *reinterpret_cast<const float4*>(&lds[i * LDS_PITCH + n0]);
        float4 wv = *reinterpret_cast<const float4*>(&W2[i * 64 + c20]);
        float h[4] = {hv.x, hv.y, hv.z, hv.w};
        float w[4] = {wv.x, wv.y, wv.z, wv.w};
#pragma unroll
        for (int a = 0; a < 4; ++a)
#pragma unroll
            for (int b = 0; b < 4; ++b)
                acc2[a][b] += h[a] * w[b];
    }

    float4 bb = *reinterpret_cast<const float4*>(&b2[c20]);
#pragma unroll
    for (int a = 0; a < 4; ++a) {
        int node = nbase + n0 + a;
        if (node < N) {
            float4 o;
            o.x = acc2[a][0] + bb.x;
            o.y = acc2[a][1] + bb.y;
            o.z = acc2[a][2] + bb.z;
            o.w = acc2[a][3] + bb.w;
            *reinterpret_cast<float4*>(&out[(size_t)node * D + c20]) = o;
        }
    }
}

// ---------------------------------------------------------------------------
extern "C" void kernel_launch(void* const* d_in, const int* in_sizes, int n_in,
                              void* d_out, int out_size, void* d_ws, size_t ws_size,
                              hipStream_t stream)
{
    const int*   edge_index = (const int*)d_in[0];
    const float* edge_attr  = (const float*)d_in[1];
    const int*   sf_index   = (const int*)d_in[3];
    const float* sf_attr    = (const float*)d_in[4];
    const float* W1         = (const float*)d_in[5];
    const float* b1         = (const float*)d_in[6];
    const float* W2         = (const float*)d_in[7];
    const float* b2         = (const float*)d_in[8];
    float* out = (float*)d_out;

    int E  = in_sizes[0] / 2;
    int Es = in_sizes[3] / 2;
    int N  = out_size / D;
    int L  = 2 * E + 2 * Es;   // total CSR entries
    int T  = 3 * N;            // total segments

    float* flow = (float*)d_ws;                       // N*192 f32
    size_t flow_elems = (size_t)N * 192;

    size_t required = flow_elems * 4 + (size_t)L * 4 + ((size_t)3 * T + 1) * 4;

    if (ws_size >= required) {
        int* list = (int*)(flow + flow_elems);        // L
        int* cnt  = list + L;                         // T
        int* cur  = cnt + T;                          // T
        int* off  = cur + T;                          // T+1

        hipMemsetAsync(cnt, 0, (size_t)2 * T * sizeof(int), stream);  // cnt+cur

        count_temporal_kernel<<<(E + 255) / 256, 256, 0, stream>>>(edge_index, cnt, E, N);
        count_sf_kernel<<<(Es + 255) / 256, 256, 0, stream>>>(sf_index, cnt, Es, N);
        scan_kernel<<<1, 1024, 0, stream>>>(cnt, off, T);
        fill_temporal_kernel<<<(E + 255) / 256, 256, 0, stream>>>(edge_index, off, cur, list, E, N);
        fill_sf_kernel<<<(Es + 255) / 256, 256, 0, stream>>>(sf_index, off, cur, list, Es, N);
        {
            long long threads = (long long)T * 64;
            int blocks = (int)((threads + 255) / 256);
            gather_kernel<<<blocks, 256, 0, stream>>>(edge_attr, sf_attr, off, list, flow, N);
        }
    } else {
        // fallback: atomic scatter into flow + counts, then normalize
        float* cntf = flow + flow_elems;              // 3N f32
        hipMemsetAsync(d_ws, 0, (flow_elems + (size_t)T) * sizeof(float), stream);
        {
            long long threads = (long long)E * 16;
            scatter_temporal_fb_kernel<<<(int)((threads + 255) / 256), 256, 0, stream>>>(
                edge_index, edge_attr, flow, cntf, E, N);
        }
        {
            long long threads = (long long)Es * 16;
            scatter_sf_fb_kernel<<<(int)((threads + 255) / 256), 256, 0, stream>>>(
                sf_index, sf_attr, flow, cntf, Es, N);
        }
        normalize_fb_kernel<<<(N * 192 + 255) / 256, 256, 0, stream>>>(flow, cntf, N);
    }

    {
        int blocks = (N + MLP_NODES - 1) / MLP_NODES;
        mlp_kernel<<<blocks, 256, 0, stream>>>(flow, W1, b1, W2, b2, out, N);
    }
}

// Round 3
// 534.338 us; speedup vs baseline: 4.2256x; 1.3458x over previous
//
#include <hip/hip_runtime.h>
#include <hip/hip_bf16.h>
#include <cstdint>

// ---------------------------------------------------------------------------
// InitialContextualNodeModel — CSR-gather version, hierarchical scan
//   flow[n] = [ fwd_mean(n) | frame_mean(n) | bwd_mean(n) ]   (192 f32)
//   out = relu(flow @ W1 + b1) @ W2 + b2
// Sections: s=0 fwd (key=future), s=1 frame (keys early+later), s=2 bwd (key=past)
// ---------------------------------------------------------------------------

#define D 64

// ---- degree counting -------------------------------------------------------
__global__ __launch_bounds__(256) void count_temporal_kernel(
    const int* __restrict__ ei, int* __restrict__ cnt, int E, int N)
{
    int e = blockIdx.x * blockDim.x + threadIdx.x;
    if (e >= E) return;
    int past = ei[e];
    int fut  = ei[E + e];
    atomicAdd(&cnt[fut], 1);            // s=0
    atomicAdd(&cnt[2 * N + past], 1);   // s=2
}

__global__ __launch_bounds__(256) void count_sf_kernel(
    const int* __restrict__ ei, int* __restrict__ cnt, int Es, int N)
{
    int e = blockIdx.x * blockDim.x + threadIdx.x;
    if (e >= Es) return;
    atomicAdd(&cnt[N + ei[e]], 1);        // s=1 early
    atomicAdd(&cnt[N + ei[Es + e]], 1);   // s=1 later
}

// ---- hierarchical exclusive scan (T elements, 1024 per block) --------------
__global__ __launch_bounds__(256) void block_sums_kernel(
    const int* __restrict__ cnt, int* __restrict__ bsum, int T)
{
    __shared__ int lds[256];
    int t = threadIdx.x;
    int base = blockIdx.x * 1024 + t * 4;
    int s = 0;
#pragma unroll
    for (int u = 0; u < 4; ++u) {
        int i = base + u;
        if (i < T) s += cnt[i];
    }
    lds[t] = s;
    __syncthreads();
    for (int d = 128; d > 0; d >>= 1) {
        if (t < d) lds[t] += lds[t + d];
        __syncthreads();
    }
    if (t == 0) bsum[blockIdx.x] = lds[0];
}

__global__ __launch_bounds__(1024) void scan_bsums_kernel(
    const int* __restrict__ bsum, int* __restrict__ boff, int nb)
{
    __shared__ int lds[1024];
    int t = threadIdx.x;
    int s = (t < nb) ? bsum[t] : 0;
    lds[t] = s;
    __syncthreads();
    for (int d = 1; d < 1024; d <<= 1) {
        int v = (t >= d) ? lds[t - d] : 0;
        __syncthreads();
        lds[t] += v;
        __syncthreads();
    }
    if (t < nb) boff[t] = lds[t] - s;   // exclusive
}

__global__ __launch_bounds__(256) void scan_final_kernel(
    const int* __restrict__ cnt, const int* __restrict__ boff,
    int* __restrict__ off, int T)
{
    __shared__ int lds[256];
    int t = threadIdx.x;
    int base = blockIdx.x * 1024 + t * 4;
    int v[4];
    int s = 0;
#pragma unroll
    for (int u = 0; u < 4; ++u) {
        int i = base + u;
        v[u] = (i < T) ? cnt[i] : 0;
        s += v[u];
    }
    lds[t] = s;
    __syncthreads();
    for (int d = 1; d < 256; d <<= 1) {
        int x = (t >= d) ? lds[t - d] : 0;
        __syncthreads();
        lds[t] += x;
        __syncthreads();
    }
    int excl = lds[t] - s + boff[blockIdx.x];
#pragma unroll
    for (int u = 0; u < 4; ++u) {
        int i = base + u;
        if (i < T) off[i] = excl;
        excl += v[u];
    }
}

// ---- CSR fill: bump off[] in place (after fill, off[g] == orig off[g+1]) ---
__global__ __launch_bounds__(256) void fill_temporal_kernel(
    const int* __restrict__ ei, int* __restrict__ off,
    int* __restrict__ list, int E, int N)
{
    int e = blockIdx.x * blockDim.x + threadIdx.x;
    if (e >= E) return;
    int past = ei[e];
    int fut  = ei[E + e];
    list[atomicAdd(&off[fut], 1)] = e;            // s=0
    list[atomicAdd(&off[2 * N + past], 1)] = e;   // s=2
}

__global__ __launch_bounds__(256) void fill_sf_kernel(
    const int* __restrict__ ei, int* __restrict__ off,
    int* __restrict__ list, int Es, int N)
{
    int e = blockIdx.x * blockDim.x + threadIdx.x;
    if (e >= Es) return;
    list[atomicAdd(&off[N + ei[e]], 1)] = e;
    list[atomicAdd(&off[N + ei[Es + e]], 1)] = e;
}

// ---- gather: one wave per (section,node) segment ---------------------------
// off[] has been bumped: segment g spans [ (g? off[g-1] : 0), off[g] )
__global__ __launch_bounds__(256) void gather_kernel(
    const float* __restrict__ edge_attr, const float* __restrict__ sf_attr,
    const int* __restrict__ off, const int* __restrict__ list,
    float* __restrict__ flow, int N)
{
    int wid  = (blockIdx.x * 256 + threadIdx.x) >> 6;   // segment id
    int lane = threadIdx.x & 63;                        // feature
    if (wid >= 3 * N) return;
    int s = wid / N;
    int node = wid - s * N;
    const float* attr = (s == 1) ? sf_attr : edge_attr;

    int k0 = (wid == 0) ? 0 : off[wid - 1];
    int k1 = off[wid];
    float acc = 0.0f;
    int k = k0;
    for (; k + 3 < k1; k += 4) {
        int e0 = list[k], e1 = list[k + 1], e2 = list[k + 2], e3 = list[k + 3];
        float v0 = attr[(size_t)e0 * D + lane];
        float v1 = attr[(size_t)e1 * D + lane];
        float v2 = attr[(size_t)e2 * D + lane];
        float v3 = attr[(size_t)e3 * D + lane];
        acc += v0 + v1 + v2 + v3;
    }
    for (; k < k1; ++k)
        acc += attr[(size_t)list[k] * D + lane];

    int deg = k1 - k0;
    float inv = 1.0f / fmaxf((float)deg, 1.0f);
    flow[(size_t)node * 192 + s * D + lane] = acc * inv;
}

// ---- fused MLP: 64 nodes/block, flow^T staged in LDS -----------------------
#define MLP_NODES 64
#define LDS_PITCH 65

__global__ __launch_bounds__(256) void mlp_kernel(
    const float* __restrict__ flow,   // [N][192] means
    const float* __restrict__ W1, const float* __restrict__ b1,
    const float* __restrict__ W2, const float* __restrict__ b2,
    float* __restrict__ out, int N)
{
    __shared__ float lds[192 * LDS_PITCH];

    int t = threadIdx.x;
    int nbase = blockIdx.x * MLP_NODES;

    // Phase 1: flow^T into LDS, float4 loads
    const float4* flow4 = reinterpret_cast<const float4*>(flow);
    for (int idx = t; idx < MLP_NODES * 48; idx += 256) {
        int ln = idx / 48;
        int q  = idx - ln * 48;
        int node = nbase + ln;
        float4 v = make_float4(0.f, 0.f, 0.f, 0.f);
        if (node < N) v = flow4[(size_t)node * 48 + q];
        int i = q * 4;
        lds[(i + 0) * LDS_PITCH + ln] = v.x;
        lds[(i + 1) * LDS_PITCH + ln] = v.y;
        lds[(i + 2) * LDS_PITCH + ln] = v.z;
        lds[(i + 3) * LDS_PITCH + ln] = v.w;
    }
    __syncthreads();

    // Phase 2: h = relu(flow @ W1 + b1).  M=64, Ncols=128, K=192
    int tn = t & 15;
    int tc = t >> 4;
    int n0 = tn * 4;
    int c0 = tc * 8;

    float acc[4][8];
#pragma unroll
    for (int a = 0; a < 4; ++a)
#pragma unroll
        for (int b = 0; b < 8; ++b) acc[a][b] = 0.0f;

    for (int i = 0; i < 192; ++i) {
        float4 fv = *reinterpret_cast<const float4*>(&lds[i * LDS_PITCH + n0]);
        float4 wa = *reinterpret_cast<const float4*>(&W1[i * 128 + c0]);
        float4 wb = *reinterpret_cast<const float4*>(&W1[i * 128 + c0 + 4]);
        float f[4] = {fv.x, fv.y, fv.z, fv.w};
        float w[8] = {wa.x, wa.y, wa.z, wa.w, wb.x, wb.y, wb.z, wb.w};
#pragma unroll
        for (int a = 0; a < 4; ++a)
#pragma unroll
            for (int b = 0; b < 8; ++b)
                acc[a][b] += f[a] * w[b];
    }
    __syncthreads();

#pragma unroll
    for (int b = 0; b < 8; ++b) {
        int col = c0 + b;
        float bias = b1[col];
        float4 hv;
        hv.x = fmaxf(acc[0][b] + bias, 0.0f);
        hv.y = fmaxf(acc[1][b] + bias, 0.0f);
        hv.z = fmaxf(acc[2][b] + bias, 0.0f);
        hv.w = fmaxf(acc[3][b] + bias, 0.0f);
        *reinterpret_cast<float4*>(&lds[col * LDS_PITCH + n0]) = hv;
    }
    __syncthreads();

    // Phase 3: out = h @ W2 + b2.  K=128
    int c20 = tc * 4;
    float acc2[4][4];
#pragma unroll
    for (int a = 0; a < 4; ++a)
#pragma unroll
        for (int b = 0; b < 4; ++b) acc2[a][b] = 0.0f;

    for (int i = 0; i < 128; ++i) {
        float4 hv = *reinterpret_cast<const float4*>(&lds[i * LDS_PITCH + n0]);
        float4 wv = *reinterpret_cast<const float4*>(&W2[i * 64 + c20]);
        float h[4] = {hv.x, hv.y, hv.z, hv.w};
        float w[4] = {wv.x, wv.y, wv.z, wv.w};
#pragma unroll
        for (int a = 0; a < 4; ++a)
#pragma unroll
            for (int b = 0; b < 4; ++b)
                acc2[a][b] += h[a] * w[b];
    }

    float4 bb = *reinterpret_cast<const float4*>(&b2[c20]);
#pragma unroll
    for (int a = 0; a < 4; ++a) {
        int node = nbase + n0 + a;
        if (node < N) {
            float4 o;
            o.x = acc2[a][0] + bb.x;
            o.y = acc2[a][1] + bb.y;
            o.z = acc2[a][2] + bb.z;
            o.w = acc2[a][3] + bb.w;
            *reinterpret_cast<float4*>(&out[(size_t)node * D + c20]) = o;
        }
    }
}

// ---------------------------------------------------------------------------
extern "C" void kernel_launch(void* const* d_in, const int* in_sizes, int n_in,
                              void* d_out, int out_size, void* d_ws, size_t ws_size,
                              hipStream_t stream)
{
    const int*   edge_index = (const int*)d_in[0];
    const float* edge_attr  = (const float*)d_in[1];
    const int*   sf_index   = (const int*)d_in[3];
    const float* sf_attr    = (const float*)d_in[4];
    const float* W1         = (const float*)d_in[5];
    const float* b1         = (const float*)d_in[6];
    const float* W2         = (const float*)d_in[7];
    const float* b2         = (const float*)d_in[8];
    float* out = (float*)d_out;

    int E  = in_sizes[0] / 2;
    int Es = in_sizes[3] / 2;
    int N  = out_size / D;
    int L  = 2 * E + 2 * Es;       // total CSR entries
    int T  = 3 * N;                // total segments
    int nb = (T + 1023) / 1024;    // scan blocks

    float* flow = (float*)d_ws;                   // N*192 f32
    size_t flow_elems = (size_t)N * 192;

    int* list = (int*)(flow + flow_elems);        // L
    int* cnt  = list + L;                         // T
    int* off  = cnt + T;                          // T
    int* bsum = off + T;                          // nb
    int* boff = bsum + nb;                        // nb

    hipMemsetAsync(cnt, 0, (size_t)T * sizeof(int), stream);

    count_temporal_kernel<<<(E + 255) / 256, 256, 0, stream>>>(edge_index, cnt, E, N);
    count_sf_kernel<<<(Es + 255) / 256, 256, 0, stream>>>(sf_index, cnt, Es, N);

    block_sums_kernel<<<nb, 256, 0, stream>>>(cnt, bsum, T);
    scan_bsums_kernel<<<1, 1024, 0, stream>>>(bsum, boff, nb);
    scan_final_kernel<<<nb, 256, 0, stream>>>(cnt, boff, off, T);

    fill_temporal_kernel<<<(E + 255) / 256, 256, 0, stream>>>(edge_index, off, list, E, N);
    fill_sf_kernel<<<(Es + 255) / 256, 256, 0, stream>>>(sf_index, off, list, Es, N);

    {
        long long threads = (long long)T * 64;
        int blocks = (int)((threads + 255) / 256);
        gather_kernel<<<blocks, 256, 0, stream>>>(edge_attr, sf_attr, off, list, flow, N);
    }
    {
        int blocks = (N + MLP_NODES - 1) / MLP_NODES;
        mlp_kernel<<<blocks, 256, 0, stream>>>(flow, W1, b1, W2, b2, out, N);
    }
}

// Round 4
// 523.588 us; speedup vs baseline: 4.3124x; 1.0205x over previous
//
#include <hip/hip_runtime.h>
#include <hip/hip_bf16.h>
#include <cstdint>

// ---------------------------------------------------------------------------
// InitialContextualNodeModel — CSR-gather, float4 gather (4 edges/wave-load)
//   flow[n] = [ fwd_mean(n) | frame_mean(n) | bwd_mean(n) ]   (192 f32)
//   out = relu(flow @ W1 + b1) @ W2 + b2
// Sections: s=0 fwd (key=future), s=1 frame (keys early+later), s=2 bwd (key=past)
// ---------------------------------------------------------------------------

#define D 64

// ---- degree counting (both edge arrays in one dispatch) --------------------
__global__ __launch_bounds__(256) void count_all_kernel(
    const int* __restrict__ ei, const int* __restrict__ sfi,
    int* __restrict__ cnt, int E, int Es, int N)
{
    int t = blockIdx.x * blockDim.x + threadIdx.x;
    if (t < E) {
        atomicAdd(&cnt[ei[E + t]], 1);          // s=0 fwd (future)
        atomicAdd(&cnt[2 * N + ei[t]], 1);      // s=2 bwd (past)
    } else {
        int e = t - E;
        if (e < Es) {
            atomicAdd(&cnt[N + sfi[e]], 1);       // s=1 early
            atomicAdd(&cnt[N + sfi[Es + e]], 1);  // s=1 later
        }
    }
}

// ---- hierarchical exclusive scan (T elements, 1024 per block) --------------
__global__ __launch_bounds__(256) void block_sums_kernel(
    const int* __restrict__ cnt, int* __restrict__ bsum, int T)
{
    __shared__ int lds[256];
    int t = threadIdx.x;
    int base = blockIdx.x * 1024 + t * 4;
    int s = 0;
#pragma unroll
    for (int u = 0; u < 4; ++u) {
        int i = base + u;
        if (i < T) s += cnt[i];
    }
    lds[t] = s;
    __syncthreads();
    for (int d = 128; d > 0; d >>= 1) {
        if (t < d) lds[t] += lds[t + d];
        __syncthreads();
    }
    if (t == 0) bsum[blockIdx.x] = lds[0];
}

__global__ __launch_bounds__(1024) void scan_bsums_kernel(
    const int* __restrict__ bsum, int* __restrict__ boff, int nb)
{
    __shared__ int lds[1024];
    int t = threadIdx.x;
    int s = (t < nb) ? bsum[t] : 0;
    lds[t] = s;
    __syncthreads();
    for (int d = 1; d < 1024; d <<= 1) {
        int v = (t >= d) ? lds[t - d] : 0;
        __syncthreads();
        lds[t] += v;
        __syncthreads();
    }
    if (t < nb) boff[t] = lds[t] - s;   // exclusive
}

__global__ __launch_bounds__(256) void scan_final_kernel(
    const int* __restrict__ cnt, const int* __restrict__ boff,
    int* __restrict__ off, int T)
{
    __shared__ int lds[256];
    int t = threadIdx.x;
    int base = blockIdx.x * 1024 + t * 4;
    int v[4];
    int s = 0;
#pragma unroll
    for (int u = 0; u < 4; ++u) {
        int i = base + u;
        v[u] = (i < T) ? cnt[i] : 0;
        s += v[u];
    }
    lds[t] = s;
    __syncthreads();
    for (int d = 1; d < 256; d <<= 1) {
        int x = (t >= d) ? lds[t - d] : 0;
        __syncthreads();
        lds[t] += x;
        __syncthreads();
    }
    int excl = lds[t] - s + boff[blockIdx.x];
#pragma unroll
    for (int u = 0; u < 4; ++u) {
        int i = base + u;
        if (i < T) off[i] = excl;
        excl += v[u];
    }
}

// ---- CSR fill: bump off[] in place (after fill, off[g] == orig off[g+1]) ---
__global__ __launch_bounds__(256) void fill_all_kernel(
    const int* __restrict__ ei, const int* __restrict__ sfi,
    int* __restrict__ off, int* __restrict__ list, int E, int Es, int N)
{
    int t = blockIdx.x * blockDim.x + threadIdx.x;
    if (t < E) {
        list[atomicAdd(&off[ei[E + t]], 1)] = t;          // s=0
        list[atomicAdd(&off[2 * N + ei[t]], 1)] = t;      // s=2
    } else {
        int e = t - E;
        if (e < Es) {
            list[atomicAdd(&off[N + sfi[e]], 1)] = e;
            list[atomicAdd(&off[N + sfi[Es + e]], 1)] = e;
        }
    }
}

// ---- gather: one wave per segment, 4 edge-rows per load instruction --------
// off[] has been bumped: segment g spans [ (g? off[g-1] : 0), off[g] )
__global__ __launch_bounds__(256) void gather_kernel(
    const float* __restrict__ edge_attr, const float* __restrict__ sf_attr,
    const int* __restrict__ off, const int* __restrict__ list,
    float* __restrict__ flow, int N)
{
    int wid  = (blockIdx.x * 256 + threadIdx.x) >> 6;   // segment id
    int lane = threadIdx.x & 63;
    if (wid >= 3 * N) return;
    int s = wid / N;
    int node = wid - s * N;
    const float4* attr4 = reinterpret_cast<const float4*>((s == 1) ? sf_attr : edge_attr);

    int slot = lane >> 4;   // 0..3 : which edge of the group of 4
    int quad = lane & 15;   // 0..15 : which float4 of the 64-f row

    int k0 = (wid == 0) ? 0 : off[wid - 1];
    int k1 = off[wid];

    float ax = 0.f, ay = 0.f, az = 0.f, aw = 0.f;
    float bx = 0.f, by = 0.f, bz = 0.f, bw = 0.f;

    int k = k0;
    for (; k + 8 <= k1; k += 8) {
        int ea = list[k + slot];
        int eb = list[k + 4 + slot];
        float4 va = attr4[(size_t)ea * 16 + quad];
        float4 vb = attr4[(size_t)eb * 16 + quad];
        ax += va.x; ay += va.y; az += va.z; aw += va.w;
        bx += vb.x; by += vb.y; bz += vb.z; bw += vb.w;
    }
    if (k + 4 <= k1) {
        int e = list[k + slot];
        float4 v = attr4[(size_t)e * 16 + quad];
        ax += v.x; ay += v.y; az += v.z; aw += v.w;
        k += 4;
    }
    if (k + slot < k1) {
        int e = list[k + slot];
        float4 v = attr4[(size_t)e * 16 + quad];
        bx += v.x; by += v.y; bz += v.z; bw += v.w;
    }
    ax += bx; ay += by; az += bz; aw += bw;

    // reduce across the 4 slots (lane bits 4 and 5)
    ax += __shfl_xor(ax, 16); ay += __shfl_xor(ay, 16);
    az += __shfl_xor(az, 16); aw += __shfl_xor(aw, 16);
    ax += __shfl_xor(ax, 32); ay += __shfl_xor(ay, 32);
    az += __shfl_xor(az, 32); aw += __shfl_xor(aw, 32);

    if (slot == 0) {
        int deg = k1 - k0;
        float inv = 1.0f / fmaxf((float)deg, 1.0f);
        float4 o = make_float4(ax * inv, ay * inv, az * inv, aw * inv);
        reinterpret_cast<float4*>(flow)[(size_t)node * 48 + s * 16 + quad] = o;
    }
}

// ---- fused MLP: 64 nodes/block, flow^T staged in LDS -----------------------
#define MLP_NODES 64
#define LDS_PITCH 65

__global__ __launch_bounds__(256) void mlp_kernel(
    const float* __restrict__ flow,   // [N][192] means
    const float* __restrict__ W1, const float* __restrict__ b1,
    const float* __restrict__ W2, const float* __restrict__ b2,
    float* __restrict__ out, int N)
{
    __shared__ float lds[192 * LDS_PITCH];

    int t = threadIdx.x;
    int nbase = blockIdx.x * MLP_NODES;

    // Phase 1: flow^T into LDS, float4 loads
    const float4* flow4 = reinterpret_cast<const float4*>(flow);
    for (int idx = t; idx < MLP_NODES * 48; idx += 256) {
        int ln = idx / 48;
        int q  = idx - ln * 48;
        int node = nbase + ln;
        float4 v = make_float4(0.f, 0.f, 0.f, 0.f);
        if (node < N) v = flow4[(size_t)node * 48 + q];
        int i = q * 4;
        lds[(i + 0) * LDS_PITCH + ln] = v.x;
        lds[(i + 1) * LDS_PITCH + ln] = v.y;
        lds[(i + 2) * LDS_PITCH + ln] = v.z;
        lds[(i + 3) * LDS_PITCH + ln] = v.w;
    }
    __syncthreads();

    // Phase 2: h = relu(flow @ W1 + b1).  M=64, Ncols=128, K=192
    int tn = t & 15;
    int tc = t >> 4;
    int n0 = tn * 4;
    int c0 = tc * 8;

    float acc[4][8];
#pragma unroll
    for (int a = 0; a < 4; ++a)
#pragma unroll
        for (int b = 0; b < 8; ++b) acc[a][b] = 0.0f;

    for (int i = 0; i < 192; ++i) {
        float4 fv = *reinterpret_cast<const float4*>(&lds[i * LDS_PITCH + n0]);
        float4 wa = *reinterpret_cast<const float4*>(&W1[i * 128 + c0]);
        float4 wb = *reinterpret_cast<const float4*>(&W1[i * 128 + c0 + 4]);
        float f[4] = {fv.x, fv.y, fv.z, fv.w};
        float w[8] = {wa.x, wa.y, wa.z, wa.w, wb.x, wb.y, wb.z, wb.w};
#pragma unroll
        for (int a = 0; a < 4; ++a)
#pragma unroll
            for (int b = 0; b < 8; ++b)
                acc[a][b] += f[a] * w[b];
    }
    __syncthreads();

#pragma unroll
    for (int b = 0; b < 8; ++b) {
        int col = c0 + b;
        float bias = b1[col];
        float4 hv;
        hv.x = fmaxf(acc[0][b] + bias, 0.0f);
        hv.y = fmaxf(acc[1][b] + bias, 0.0f);
        hv.z = fmaxf(acc[2][b] + bias, 0.0f);
        hv.w = fmaxf(acc[3][b] + bias, 0.0f);
        *reinterpret_cast<float4*>(&lds[col * LDS_PITCH + n0]) = hv;
    }
    __syncthreads();

    // Phase 3: out = h @ W2 + b2.  K=128
    int c20 = tc * 4;
    float acc2[4][4];
#pragma unroll
    for (int a = 0; a < 4; ++a)
#pragma unroll
        for (int b = 0; b < 4; ++b) acc2[a][b] = 0.0f;

    for (int i = 0; i < 128; ++i) {
        float4 hv = *reinterpret_cast<const float4*>(&lds[i * LDS_PITCH + n0]);
        float4 wv = *reinterpret_cast<const float4*>(&W2[i * 64 + c20]);
        float h[4] = {hv.x, hv.y, hv.z, hv.w};
        float w[4] = {wv.x, wv.y, wv.z, wv.w};
#pragma unroll
        for (int a = 0; a < 4; ++a)
#pragma unroll
            for (int b = 0; b < 4; ++b)
                acc2[a][b] += h[a] * w[b];
    }

    float4 bb = *reinterpret_cast<const float4*>(&b2[c20]);
#pragma unroll
    for (int a = 0; a < 4; ++a) {
        int node = nbase + n0 + a;
        if (node < N) {
            float4 o;
            o.x = acc2[a][0] + bb.x;
            o.y = acc2[a][1] + bb.y;
            o.z = acc2[a][2] + bb.z;
            o.w = acc2[a][3] + bb.w;
            *reinterpret_cast<float4*>(&out[(size_t)node * D + c20]) = o;
        }
    }
}

// ---------------------------------------------------------------------------
extern "C" void kernel_launch(void* const* d_in, const int* in_sizes, int n_in,
                              void* d_out, int out_size, void* d_ws, size_t ws_size,
                              hipStream_t stream)
{
    const int*   edge_index = (const int*)d_in[0];
    const float* edge_attr  = (const float*)d_in[1];
    const int*   sf_index   = (const int*)d_in[3];
    const float* sf_attr    = (const float*)d_in[4];
    const float* W1         = (const float*)d_in[5];
    const float* b1         = (const float*)d_in[6];
    const float* W2         = (const float*)d_in[7];
    const float* b2         = (const float*)d_in[8];
    float* out = (float*)d_out;

    int E  = in_sizes[0] / 2;
    int Es = in_sizes[3] / 2;
    int N  = out_size / D;
    int L  = 2 * E + 2 * Es;       // total CSR entries
    int T  = 3 * N;                // total segments
    int nb = (T + 1023) / 1024;    // scan blocks

    float* flow = (float*)d_ws;                   // N*192 f32
    size_t flow_elems = (size_t)N * 192;

    int* list = (int*)(flow + flow_elems);        // L
    int* cnt  = list + L;                         // T
    int* off  = cnt + T;                          // T
    int* bsum = off + T;                          // nb
    int* boff = bsum + nb;                        // nb

    hipMemsetAsync(cnt, 0, (size_t)T * sizeof(int), stream);

    {
        int tot = E + Es;
        count_all_kernel<<<(tot + 255) / 256, 256, 0, stream>>>(
            edge_index, sf_index, cnt, E, Es, N);
    }

    block_sums_kernel<<<nb, 256, 0, stream>>>(cnt, bsum, T);
    scan_bsums_kernel<<<1, 1024, 0, stream>>>(bsum, boff, nb);
    scan_final_kernel<<<nb, 256, 0, stream>>>(cnt, boff, off, T);

    {
        int tot = E + Es;
        fill_all_kernel<<<(tot + 255) / 256, 256, 0, stream>>>(
            edge_index, sf_index, off, list, E, Es, N);
    }

    {
        long long threads = (long long)T * 64;
        int blocks = (int)((threads + 255) / 256);
        gather_kernel<<<blocks, 256, 0, stream>>>(edge_attr, sf_attr, off, list, flow, N);
    }
    {
        int blocks = (N + MLP_NODES - 1) / MLP_NODES;
        mlp_kernel<<<blocks, 256, 0, stream>>>(flow, W1, b1, W2, b2, out, N);
    }
}